// Round 1
// baseline (453.999 us; speedup 1.0000x reference)
//
#include <hip/hip_runtime.h>
#include <hip/hip_bf16.h>

// Problem constants
#define BATCH   65536
#define HW      28
#define OHW     26
#define FEAT    676     // 26*26
#define KPAD    704     // 22 chunks of 32
#define FPAD    712     // +8 bf16 LDS row pad (breaks 352-dword bank stride)
#define HID     200
#define NPAD    208     // 13 tiles of 16
#define NCLS    10
#define MT      32      // images per block
#define NTHREADS 128    // 2 waves

typedef __attribute__((ext_vector_type(8))) __bf16 bf16x8;
typedef __attribute__((ext_vector_type(4))) float  f32x4;

// w1 (676x200 f32, row-major) -> w1T bf16 [NPAD][KPAD], zero-padded.
__global__ __launch_bounds__(256) void prep_w1t(const float* __restrict__ w1,
                                                unsigned short* __restrict__ w1t) {
  int idx = blockIdx.x * 256 + threadIdx.x;
  if (idx >= NPAD * KPAD) return;
  int n = idx / KPAD;
  int k = idx - n * KPAD;
  float v = (n < HID && k < FEAT) ? w1[k * HID + n] : 0.f;
  __hip_bfloat16 h = __float2bfloat16(v);
  w1t[idx] = __builtin_bit_cast(unsigned short, h);
}

__global__ __launch_bounds__(NTHREADS) void fused_fwd(
    const float* __restrict__ x, const float* __restrict__ cwp,
    const unsigned short* __restrict__ w1t, const float* __restrict__ b1,
    const float* __restrict__ w2, const float* __restrict__ b2,
    float* __restrict__ out) {
  __shared__ unsigned short feat[MT][FPAD];   // 45,568 B; reused as fp32 hidden later
  __shared__ float w2s[HID * NCLS];           // 8,000 B
  __shared__ float b1s[HID];
  __shared__ float b2s[NCLS];

  const int tid  = threadIdx.x;
  const int wave = tid >> 6;
  const int lane = tid & 63;

  // stage small params
  for (int i = tid; i < HID * NCLS; i += NTHREADS) w2s[i] = w2[i];
  for (int i = tid; i < HID; i += NTHREADS) b1s[i] = b1[i];
  if (tid < NCLS) b2s[tid] = b2[tid];
  // zero feat k-padding [676,704) (28 per row)
  for (int i = tid; i < MT * (KPAD - FEAT); i += NTHREADS) {
    feat[i / (KPAD - FEAT)][FEAT + (i % (KPAD - FEAT))] = 0;
  }

  float cw[9];
  #pragma unroll
  for (int t = 0; t < 9; ++t) cw[t] = cwp[t];

  // ---- Phase 1: conv 3x3 VALID, fp32 compute, bf16 store to LDS ----
  // task = output-row job: (image m, out-row i); 32*26 = 832 tasks.
  for (int task = tid; task < MT * OHW; task += NTHREADS) {
    int m = task & (MT - 1);
    int i = task >> 5;
    long gm = (long)blockIdx.x * MT + m;
    const float4* xr = (const float4*)(x + gm * (HW * HW));
    float r[3][HW];
    #pragma unroll
    for (int di = 0; di < 3; ++di) {
      #pragma unroll
      for (int q = 0; q < 7; ++q) {
        float4 v = xr[(i + di) * 7 + q];
        r[di][q * 4 + 0] = v.x; r[di][q * 4 + 1] = v.y;
        r[di][q * 4 + 2] = v.z; r[di][q * 4 + 3] = v.w;
      }
    }
    // i*26 is even -> 13 aligned dword writes of bf16 pairs
    unsigned int* dst = (unsigned int*)&feat[m][i * OHW];
    #pragma unroll
    for (int jp = 0; jp < 13; ++jp) {
      float s0 = 0.f, s1 = 0.f;
      #pragma unroll
      for (int di = 0; di < 3; ++di) {
        #pragma unroll
        for (int dj = 0; dj < 3; ++dj) {
          s0 += cw[di * 3 + dj] * r[di][2 * jp + dj];
          s1 += cw[di * 3 + dj] * r[di][2 * jp + 1 + dj];
        }
      }
      __hip_bfloat16 h0 = __float2bfloat16(s0);
      __hip_bfloat16 h1 = __float2bfloat16(s1);
      dst[jp] = (unsigned int)__builtin_bit_cast(unsigned short, h0)
              | ((unsigned int)__builtin_bit_cast(unsigned short, h1) << 16);
    }
  }
  __syncthreads();

  // ---- Phase 2: GEMM1 hidden = relu(feat @ w1 + b1), 16x16x32 bf16 MFMA ----
  // A: lane holds feat[m = lane&15][k = (lane>>4)*8 + j]; wave w owns rows w*16..w*16+15.
  // B: lane holds w1T[n = lane&15][same k] (w1T is B^T layout, m90-m97 verified).
  // C/D: col = lane&15 (n), row = (lane>>4)*4 + reg (m).  [m89/m91 verified]
  const int ln   = lane & 15;
  const int qd   = lane >> 4;
  const int mrow = wave * 16 + ln;
  const int koff = qd * 8;

  f32x4 acc[13];
  #pragma unroll
  for (int nt = 0; nt < 13; ++nt) acc[nt] = (f32x4){0.f, 0.f, 0.f, 0.f};

  for (int kc = 0; kc < 22; ++kc) {
    int k0 = kc * 32 + koff;
    bf16x8 a = *(const bf16x8*)(&feat[mrow][k0]);
    #pragma unroll
    for (int nt = 0; nt < 13; ++nt) {
      bf16x8 b = *(const bf16x8*)(w1t + (size_t)(nt * 16 + ln) * KPAD + k0);
      acc[nt] = __builtin_amdgcn_mfma_f32_16x16x32_bf16(a, b, acc[nt], 0, 0, 0);
    }
  }

  // bias + relu; store hidden into reused feat LDS. hid row m lives exactly in
  // feat row m's bytes (356 floats per 712-ushort row) -> each wave writes only
  // its own 16 rows, no cross-wave race before the barrier.
  float* hid = (float*)&feat[0][0];
  #pragma unroll
  for (int nt = 0; nt < 13; ++nt) {
    int n = nt * 16 + ln;
    if (n < HID) {
      float bias = b1s[n];
      #pragma unroll
      for (int rr = 0; rr < 4; ++rr) {
        int m = wave * 16 + qd * 4 + rr;
        hid[m * (FPAD / 2) + n] = fmaxf(acc[nt][rr] + bias, 0.f);
      }
    }
  }
  __syncthreads();

  // ---- Phase 3: GEMM2 out = hidden @ w2 + b2 (fp32 VALU, tiny) ----
  for (int o = tid; o < MT * NCLS; o += NTHREADS) {
    int m = o / NCLS, c = o - m * NCLS;
    float s = b2s[c];
    const float* hrow = hid + m * (FPAD / 2);
    #pragma unroll 8
    for (int n = 0; n < HID; ++n) s += hrow[n] * w2s[n * NCLS + c];
    out[((long)blockIdx.x * MT + m) * NCLS + c] = s;
  }
}

extern "C" void kernel_launch(void* const* d_in, const int* in_sizes, int n_in,
                              void* d_out, int out_size, void* d_ws, size_t ws_size,
                              hipStream_t stream) {
  const float* x  = (const float*)d_in[0];
  const float* cw = (const float*)d_in[1];
  const float* w1 = (const float*)d_in[2];
  const float* b1 = (const float*)d_in[3];
  const float* w2 = (const float*)d_in[4];
  const float* b2 = (const float*)d_in[5];
  unsigned short* w1t = (unsigned short*)d_ws;   // needs 208*704*2 = 292,864 B
  float* out = (float*)d_out;

  const int prep_elems = NPAD * KPAD;
  hipLaunchKernelGGL(prep_w1t, dim3((prep_elems + 255) / 256), dim3(256), 0, stream,
                     w1, w1t);
  hipLaunchKernelGGL(fused_fwd, dim3(BATCH / MT), dim3(NTHREADS), 0, stream,
                     x, cw, w1t, b1, w2, b2, out);
}